// Round 6
// baseline (33.218 us; speedup 1.0000x reference)
//
#include <hip/hip_runtime.h>

#define TT 4096
#define DD 256

typedef __attribute__((ext_vector_type(8))) short short8;
typedef __attribute__((ext_vector_type(4))) float f32x4;
typedef __attribute__((ext_vector_type(2))) unsigned int u32x2;
typedef __attribute__((ext_vector_type(4))) unsigned int u32x4;

__device__ __forceinline__ unsigned int f2bf(float f) {
    unsigned int u = __builtin_bit_cast(unsigned int, f);
    u += 0x7fffu + ((u >> 16) & 1u);          // RNE
    return u >> 16;
}

#define INV_E 0.36787944117144233f
#define LOG2R (-0.5307378454346229f)          // log2(exp(-1/e))

// ---- K1: z[b][d][t] = w[t] * (x @ W^T + b)[t][d]  (bf16, stored transposed) ----
__global__ __launch_bounds__(256, 3)
void k1(const float* __restrict__ x, const float* __restrict__ mask,
        const float* __restrict__ Win, const float* __restrict__ bin,
        unsigned short* __restrict__ zw)
{
    __shared__ union {
        struct {
            unsigned short xl[2][64][40];     // x chunk bf16, pitch 40 (10.2 KB)
            unsigned short wl[2][128][40];    // W chunk bf16, pitch 40 (20.5 KB)
        } s;
        unsigned int T[128][36];              // epilogue transpose, pitch 36 w (18.4 KB)
    } U;

    const int tid = threadIdx.x;
    const int cpx = gridDim.x >> 3;
    const int wgs = ((int)blockIdx.x & 7) * cpx + ((int)blockIdx.x >> 3);
    const int np  = wgs & 1;
    const int tl  = wgs >> 1;
    const int b   = tl >> 6;
    const int r0  = (tl & 63) * 64;
    const int n0  = np * 128;

    const int w = tid >> 6, lane = tid & 63, lr = lane & 15, lg = lane >> 4;
    const int wr = w >> 1, wc = w & 1;

    const int xt = tid >> 2, xc = tid & 3;    // x staging: row t, 8 floats at k=8*xc
    const int wn = tid >> 1, wh = tid & 1;    // W staging: row n, 16 floats at k=16*wh

    const float* xp = x + ((size_t)(b * TT + r0 + xt)) * DD + 8 * xc;
    const float* wp = Win + (size_t)(n0 + wn) * DD + 16 * wh;

    float xr[8], wv_[16];
    auto xload = [&](int ch) {
        float4 a = *(const float4*)(xp + 32 * ch);
        float4 c = *(const float4*)(xp + 32 * ch + 4);
        xr[0]=a.x; xr[1]=a.y; xr[2]=a.z; xr[3]=a.w;
        xr[4]=c.x; xr[5]=c.y; xr[6]=c.z; xr[7]=c.w;
    };
    auto wload = [&](int ch) {
        #pragma unroll
        for (int i = 0; i < 4; ++i) {
            float4 v = *(const float4*)(wp + 32 * ch + 4 * i);
            wv_[4*i]=v.x; wv_[4*i+1]=v.y; wv_[4*i+2]=v.z; wv_[4*i+3]=v.w;
        }
    };
    auto xstore = [&](int buf) {
        u32x4 p;
        p.x = f2bf(xr[0]) | (f2bf(xr[1]) << 16);
        p.y = f2bf(xr[2]) | (f2bf(xr[3]) << 16);
        p.z = f2bf(xr[4]) | (f2bf(xr[5]) << 16);
        p.w = f2bf(xr[6]) | (f2bf(xr[7]) << 16);
        *(u32x4*)&U.s.xl[buf][xt][8 * xc] = p;
    };
    auto wstore = [&](int buf) {
        u32x4 p, q;
        p.x = f2bf(wv_[0])  | (f2bf(wv_[1])  << 16);
        p.y = f2bf(wv_[2])  | (f2bf(wv_[3])  << 16);
        p.z = f2bf(wv_[4])  | (f2bf(wv_[5])  << 16);
        p.w = f2bf(wv_[6])  | (f2bf(wv_[7])  << 16);
        q.x = f2bf(wv_[8])  | (f2bf(wv_[9])  << 16);
        q.y = f2bf(wv_[10]) | (f2bf(wv_[11]) << 16);
        q.z = f2bf(wv_[12]) | (f2bf(wv_[13]) << 16);
        q.w = f2bf(wv_[14]) | (f2bf(wv_[15]) << 16);
        *(u32x4*)&U.s.wl[buf][wn][16 * wh]     = p;
        *(u32x4*)&U.s.wl[buf][wn][16 * wh + 8] = q;
    };

    f32x4 acc[2][4];
    #pragma unroll
    for (int m = 0; m < 2; ++m)
        #pragma unroll
        for (int n = 0; n < 4; ++n) acc[m][n] = (f32x4){0.f, 0.f, 0.f, 0.f};

    xload(0); wload(0);
    xstore(0); wstore(0);
    __syncthreads();

    #pragma unroll 1
    for (int ch = 0; ch < 8; ++ch) {
        const int buf = ch & 1;
        if (ch < 7) { xload(ch + 1); wload(ch + 1); }
        short8 af[2], bfr[4];
        #pragma unroll
        for (int m = 0; m < 2; ++m)
            af[m] = *(const short8*)&U.s.xl[buf][32 * wr + 16 * m + lr][8 * lg];
        #pragma unroll
        for (int n = 0; n < 4; ++n)
            bfr[n] = *(const short8*)&U.s.wl[buf][64 * wc + 16 * n + lr][8 * lg];
        #pragma unroll
        for (int m = 0; m < 2; ++m)
            #pragma unroll
            for (int n = 0; n < 4; ++n)
                acc[m][n] = __builtin_amdgcn_mfma_f32_16x16x32_bf16(af[m], bfr[n], acc[m][n], 0, 0, 0);
        if (ch < 7) { xstore(buf ^ 1); wstore(buf ^ 1); }
        __syncthreads();
    }

    // epilogue: z = w[t]*(acc + bin), bf16, transpose to [d][t] via pitch-36 u32 buffer
    float wvv[2][4];
    #pragma unroll
    for (int m = 0; m < 2; ++m)
        #pragma unroll
        for (int j = 0; j < 4; ++j)
            wvv[m][j] = __expf(mask[b * TT + r0 + 32 * wr + 16 * m + 4 * lg + j] * INV_E);
    float bv[4];
    #pragma unroll
    for (int n = 0; n < 4; ++n) bv[n] = bin[n0 + 64 * wc + 16 * n + lr];

    #pragma unroll
    for (int m = 0; m < 2; ++m)
        #pragma unroll
        for (int n = 0; n < 4; ++n) {
            u32x2 t2;
            t2.x = f2bf((acc[m][n][0] + bv[n]) * wvv[m][0])
                 | (f2bf((acc[m][n][1] + bv[n]) * wvv[m][1]) << 16);
            t2.y = f2bf((acc[m][n][2] + bv[n]) * wvv[m][2])
                 | (f2bf((acc[m][n][3] + bv[n]) * wvv[m][3]) << 16);
            *(u32x2*)&U.T[64 * wc + 16 * n + lr][16 * wr + 8 * m + 2 * lg] = t2;
        }
    __syncthreads();
    #pragma unroll
    for (int i = 0; i < 4; ++i) {
        int idx = tid + 256 * i;
        int d = idx >> 3, c = idx & 7;
        u32x4 v = *(const u32x4*)&U.T[d][4 * c];
        *(u32x4*)(zw + ((size_t)(b * DD + n0 + d)) * TT + r0 + 8 * c) = v;
    }
}

// ---- K2: out[i][d] = sum_t r^|i-t| * z[d][t]  (banded Toeplitz, window 192) ----
__global__ __launch_bounds__(256, 4)
void k2(const unsigned short* __restrict__ zw, float* __restrict__ out)
{
    __shared__ unsigned short zl[32][200];    // z tile [d][t], pitch 200 (12.8 KB)

    const int tid = threadIdx.x;
    const int cpx = gridDim.x >> 3;
    const int wgs = ((int)blockIdx.x & 7) * cpx + ((int)blockIdx.x >> 3);
    const int dq  = wgs & 7;
    const int tl  = wgs >> 3;
    const int b   = tl >> 6;
    const int r0  = (tl & 63) * 64;
    const int t0  = r0 - 64;
    const int d0  = dq * 32;

    const int w = tid >> 6, lane = tid & 63, lr = lane & 15, lg = lane >> 4;

    // stage issue (T14: loads first, af-build overlaps, writes last)
    const int sd = tid >> 3, sc0 = tid & 7;
    const unsigned short* zp = zw + ((size_t)(b * DD + d0 + sd)) * TT;
    u32x4 sv[3];
    #pragma unroll
    for (int i = 0; i < 3; ++i) {
        int c  = sc0 + 8 * i;
        int tq = t0 + 8 * c;
        u32x4 v = (u32x4){0u, 0u, 0u, 0u};
        if (tq >= 0 && tq < TT) v = *(const u32x4*)(zp + tq);
        sv[i] = v;
    }

    // Toeplitz A-fragments in registers (48 exp2)
    short8 af[6];
    #pragma unroll
    for (int ch = 0; ch < 6; ++ch) {
        unsigned int p[4];
        #pragma unroll
        for (int pp = 0; pp < 4; ++pp) {
            int dlt0 = (16 * w + lr + 64) - (32 * ch + 8 * lg + 2 * pp);
            int dlt1 = dlt0 - 1;
            float f0 = exp2f(LOG2R * (float)((dlt0 < 0) ? -dlt0 : dlt0));
            float f1 = exp2f(LOG2R * (float)((dlt1 < 0) ? -dlt1 : dlt1));
            p[pp] = f2bf(f0) | (f2bf(f1) << 16);
        }
        af[ch] = __builtin_bit_cast(short8, (u32x4){p[0], p[1], p[2], p[3]});
    }

    #pragma unroll
    for (int i = 0; i < 3; ++i)
        *(u32x4*)&zl[sd][8 * (sc0 + 8 * i)] = sv[i];
    __syncthreads();

    f32x4 acc[2];
    acc[0] = (f32x4){0.f, 0.f, 0.f, 0.f};
    acc[1] = (f32x4){0.f, 0.f, 0.f, 0.f};

    #pragma unroll
    for (int ch = 0; ch < 6; ++ch) {
        short8 bfr[2];
        #pragma unroll
        for (int nn = 0; nn < 2; ++nn)
            bfr[nn] = *(const short8*)&zl[16 * nn + lr][8 * (4 * ch + lg)];
        #pragma unroll
        for (int nn = 0; nn < 2; ++nn)
            acc[nn] = __builtin_amdgcn_mfma_f32_16x16x32_bf16(af[ch], bfr[nn], acc[nn], 0, 0, 0);
    }

    // C/D map: row = (lane>>4)*4+j, col = lane&15  [validated rounds 2-5]
    float* ob = out + ((size_t)(b * TT + r0 + 16 * w)) * DD + d0;
    #pragma unroll
    for (int nn = 0; nn < 2; ++nn)
        #pragma unroll
        for (int j = 0; j < 4; ++j)
            ob[(4 * lg + j) * DD + 16 * nn + lr] = acc[nn][j];
}

extern "C" void kernel_launch(void* const* d_in, const int* in_sizes, int n_in,
                              void* d_out, int out_size, void* d_ws, size_t ws_size,
                              hipStream_t stream) {
    const float* x    = (const float*)d_in[0];
    const float* mask = (const float*)d_in[1];
    const float* Win  = (const float*)d_in[2];
    const float* bin  = (const float*)d_in[3];
    float* out = (float*)d_out;

    const int nb = in_sizes[0] / (TT * DD);                  // 4 batches
    unsigned short* zwp = (unsigned short*)d_ws;             // [nb][256][4096] bf16 (8 MiB)

    hipLaunchKernelGGL(k1, dim3(nb * 128), dim3(256), 0, stream, x, mask, Win, bin, zwp);
    hipLaunchKernelGGL(k2, dim3(nb * 512), dim3(256), 0, stream, zwp, out);
}